// Round 1
// baseline (10464.082 us; speedup 1.0000x reference)
//
#include <hip/hip_runtime.h>
#include <hip/hip_bf16.h>
#include <math.h>

#define NN 8192
#define DD 256
#define KSEED 5
#define CC 64
#define TK 8
#define NITERS 20
#define CSPLIT 8
#define BM 128
#define BN 128
#define BK 64

__device__ __forceinline__ bool kbetter(float v1, int i1, float v2, int i2) {
    return (v1 > v2) || ((v1 == v2) && (i1 < i2));
}

// ---------------------------------------------------------------- transpose
// in [NN][DD] -> out [DD][NN]
__global__ __launch_bounds__(256) void transpose_k(const float* __restrict__ in,
                                                   float* __restrict__ out) {
    __shared__ float t[32][33];
    int bx = blockIdx.x * 32;  // N base
    int by = blockIdx.y * 32;  // D base
    int x = threadIdx.x;       // 0..31
    int y = threadIdx.y;       // 0..7
#pragma unroll
    for (int i = 0; i < 32; i += 8)
        t[y + i][x] = in[(size_t)(bx + y + i) * DD + by + x];
    __syncthreads();
#pragma unroll
    for (int i = 0; i < 32; i += 8)
        out[(size_t)(by + y + i) * NN + bx + x] = t[x][y + i];
}

// ---------------------------------------------------------------- adjacency bitmap
__global__ __launch_bounds__(256) void adj_k(const int* __restrict__ e0,
                                             const int* __restrict__ e1,
                                             unsigned int* __restrict__ bm, int E) {
    int t = blockIdx.x * 256 + threadIdx.x;
    if (t < E) {
        unsigned code = (unsigned)e0[t] * NN + (unsigned)e1[t];
        atomicOr(&bm[code >> 5], 1u << (code & 31));
    }
}

// ---------------------------------------------------------------- kmeans init
// centT layout: [s][d][c]
__global__ __launch_bounds__(256) void kinit_k(const float* __restrict__ teacher,
                                               const int* __restrict__ initIdx,
                                               float* __restrict__ centT,
                                               float* __restrict__ cnorm) {
    int c = blockIdx.x, s = blockIdx.y;
    int t = threadIdx.x;
    int src = initIdx[s * CC + c];
    float v = teacher[(size_t)src * DD + t];
    centT[((size_t)s * DD + t) * CC + c] = v;
    __shared__ float red[256];
    red[t] = v * v;
    __syncthreads();
    for (int w = 128; w > 0; w >>= 1) {
        if (t < w) red[t] += red[t + w];
        __syncthreads();
    }
    if (t == 0) cnorm[s * CC + c] = red[0];
}

// ---------------------------------------------------------------- kmeans assign
// d2 = ||c||^2 - 2 x.c ; argmin over c (ties -> lowest c)
__global__ __launch_bounds__(256) void kassign_k(const float* __restrict__ tT,
                                                 const float* __restrict__ centT,
                                                 const float* __restrict__ cnorm,
                                                 int* __restrict__ labels) {
    __shared__ float Xs[64 * 128];  // [kk][pt] 32 KB
    __shared__ float Cs[64 * 64];   // [kk][c]  16 KB (reused for reduction)
    const int s = blockIdx.y;
    const int pB = blockIdx.x * 128;
    const int tid = threadIdx.x;
    const int tx = tid & 15;
    const int ty = tid >> 4;
    float acc[8][4];
#pragma unroll
    for (int a = 0; a < 8; a++)
#pragma unroll
        for (int b = 0; b < 4; b++) acc[a][b] = 0.f;

    for (int kt = 0; kt < DD; kt += 64) {
        __syncthreads();
#pragma unroll
        for (int m = 0; m < 8; m++) {
            int u = m * 256 + tid;
            int kk = u >> 5;
            int r4 = (u & 31) << 2;
            *(float4*)&Xs[kk * 128 + r4] =
                *(const float4*)&tT[(size_t)(kt + kk) * NN + pB + r4];
        }
#pragma unroll
        for (int m = 0; m < 4; m++) {
            int u = m * 256 + tid;
            int kk = u >> 4;
            int c4 = (u & 15) << 2;
            *(float4*)&Cs[kk * 64 + c4] =
                *(const float4*)&centT[(size_t)s * DD * CC + (size_t)(kt + kk) * CC + c4];
        }
        __syncthreads();
#pragma unroll
        for (int kk = 0; kk < 64; kk++) {
            float4 x0 = *(float4*)&Xs[kk * 128 + 4 * ty];
            float4 x1 = *(float4*)&Xs[kk * 128 + 64 + 4 * ty];
            float4 cv = *(float4*)&Cs[kk * 64 + 4 * tx];
            float xr[8] = {x0.x, x0.y, x0.z, x0.w, x1.x, x1.y, x1.z, x1.w};
            float cr[4] = {cv.x, cv.y, cv.z, cv.w};
#pragma unroll
            for (int a = 0; a < 8; a++)
#pragma unroll
                for (int b = 0; b < 4; b++) acc[a][b] = fmaf(xr[a], cr[b], acc[a][b]);
        }
    }
    __syncthreads();
    float* red = Cs;  // [128][16][2] floats = 4096
    float cn[4];
#pragma unroll
    for (int b = 0; b < 4; b++) cn[b] = cnorm[s * CC + 4 * tx + b];
#pragma unroll
    for (int a = 0; a < 8; a++) {
        float bv = INFINITY;
        int bc = 0;
#pragma unroll
        for (int b = 0; b < 4; b++) {
            float d = fmaf(-2.f, acc[a][b], cn[b]);
            if (d < bv) { bv = d; bc = 4 * tx + b; }
        }
        int p = (a < 4) ? (4 * ty + a) : (64 + 4 * ty + (a - 4));
        red[(p * 16 + tx) * 2] = bv;
        ((int*)red)[(p * 16 + tx) * 2 + 1] = bc;
    }
    __syncthreads();
    if (tid < 128) {
        float bv = INFINITY;
        int bc = 0;
        for (int t2 = 0; t2 < 16; t2++) {  // ascending c -> lowest-c tie-break
            float v = red[(tid * 16 + t2) * 2];
            int c = ((int*)red)[(tid * 16 + t2) * 2 + 1];
            if (v < bv) { bv = v; bc = c; }
        }
        labels[(size_t)s * NN + pB + tid] = bc;
    }
}

// ---------------------------------------------------------------- kmeans update: partial sums
__global__ __launch_bounds__(256) void kupd1_k(const float* __restrict__ teacher,
                                               const int* __restrict__ labels,
                                               float* __restrict__ psums,
                                               int* __restrict__ pcnts) {
    __shared__ float sums[CC * DD];  // 64 KB
    __shared__ int labs[256];
    const int b = blockIdx.x;
    const int s = blockIdx.y;
    const int tid = threadIdx.x;
    for (int i = tid; i < CC * DD; i += 256) sums[i] = 0.f;
    const int p0 = b * 256;
    labs[tid] = labels[(size_t)s * NN + p0 + tid];
    __syncthreads();
#pragma unroll 4
    for (int i = 0; i < 256; i++) {
        int lab = labs[i];
        float x = teacher[(size_t)(p0 + i) * DD + tid];
        atomicAdd(&sums[lab * DD + tid], x);  // ds_add_f32, fire-and-forget
    }
    __syncthreads();
    for (int i = tid; i < CC * DD; i += 256)
        psums[(size_t)(s * 32 + b) * CC * DD + i] = sums[i];
    if (tid < CC) {
        int cnt = 0;
        for (int i = 0; i < 256; i++) cnt += (labs[i] == tid);
        pcnts[(s * 32 + b) * CC + tid] = cnt;
    }
}

// ---------------------------------------------------------------- kmeans update: reduce + new centroids + cnorm
__global__ __launch_bounds__(256) void kupd2_k(const float* __restrict__ psums,
                                               const int* __restrict__ pcnts,
                                               float* __restrict__ centT,
                                               float* __restrict__ cnorm) {
    const int c = blockIdx.x;
    const int s = blockIdx.y;
    const int t = threadIdx.x;
    float sum = 0.f;
#pragma unroll 4
    for (int b = 0; b < 32; b++) sum += psums[((size_t)(s * 32 + b) * CC + c) * DD + t];
    int cnt = 0;
#pragma unroll
    for (int b = 0; b < 32; b++) cnt += pcnts[(s * 32 + b) * CC + c];
    float old = centT[((size_t)s * DD + t) * CC + c];
    float nv = (cnt > 0) ? (sum / (float)cnt) : old;
    centT[((size_t)s * DD + t) * CC + c] = nv;
    __shared__ float red[256];
    red[t] = nv * nv;
    __syncthreads();
    for (int w = 128; w > 0; w >>= 1) {
        if (t < w) red[t] += red[t + w];
        __syncthreads();
    }
    if (t == 0) cnorm[s * CC + c] = red[0];
}

// ---------------------------------------------------------------- fused GEMM + per-row top-8 (per column split)
__global__ __launch_bounds__(256) void topk_gemm_k(const float* __restrict__ sT,
                                                   const float* __restrict__ tT,
                                                   float* __restrict__ pv,
                                                   int* __restrict__ pi) {
    __shared__ float smem[BK * BM + BK * BN];  // 64 KB, multi-purpose
    float* As = smem;            // [BK][BM] k-major
    float* Bs = smem + BK * BM;  // [BK][BN]

    const int split = blockIdx.x;
    const int rowB = blockIdx.y * BM;
    const int tid = threadIdx.x;
    const int tx = tid & 15;
    const int ty = tid >> 4;
    const int sr = tid >> 1;  // scan row 0..127
    const int sh = tid & 1;   // scan half

    float tv[TK];
    int ti[TK];
#pragma unroll
    for (int q = 0; q < TK; q++) { tv[q] = -INFINITY; ti[q] = 0x7fffffff; }

    const int colBase = split * (NN / CSPLIT);

    for (int ct = 0; ct < NN / CSPLIT; ct += BN) {
        const int colB = colBase + ct;
        float acc[8][8];
#pragma unroll
        for (int a = 0; a < 8; a++)
#pragma unroll
            for (int b = 0; b < 8; b++) acc[a][b] = 0.f;

        for (int kt = 0; kt < DD; kt += BK) {
            __syncthreads();
#pragma unroll
            for (int m = 0; m < 8; m++) {
                int u = m * 256 + tid;
                int kk = u >> 5;
                int r4 = (u & 31) << 2;
                *(float4*)&As[kk * BM + r4] =
                    *(const float4*)&sT[(size_t)(kt + kk) * NN + rowB + r4];
                *(float4*)&Bs[kk * BN + r4] =
                    *(const float4*)&tT[(size_t)(kt + kk) * NN + colB + r4];
            }
            __syncthreads();
#pragma unroll
            for (int kk = 0; kk < BK; kk++) {
                float4 a0 = *(float4*)&As[kk * BM + 4 * ty];
                float4 a1 = *(float4*)&As[kk * BM + 64 + 4 * ty];
                float4 b0 = *(float4*)&Bs[kk * BN + 4 * tx];
                float4 b1 = *(float4*)&Bs[kk * BN + 64 + 4 * tx];
                float ar[8] = {a0.x, a0.y, a0.z, a0.w, a1.x, a1.y, a1.z, a1.w};
                float bc[8] = {b0.x, b0.y, b0.z, b0.w, b1.x, b1.y, b1.z, b1.w};
#pragma unroll
                for (int a = 0; a < 8; a++)
#pragma unroll
                    for (int b = 0; b < 8; b++)
                        acc[a][b] = fmaf(ar[a], bc[b], acc[a][b]);
            }
        }
        __syncthreads();
        // stage tile to LDS with XOR bank swizzle (+ diagonal boost)
#pragma unroll
        for (int a = 0; a < 8; a++) {
            int ra = (a < 4) ? (4 * ty + a) : (64 + 4 * ty + (a - 4));
            int grow = rowB + ra;
#pragma unroll
            for (int b = 0; b < 8; b++) {
                int cb = (b < 4) ? (4 * tx + b) : (64 + 4 * tx + (b - 4));
                float v = acc[a][b];
                if (grow == colB + cb) v += 10.f;
                smem[ra * BM + (cb ^ (ra & 31))] = v;
            }
        }
        __syncthreads();
        // per-thread running top-8 over this tile's 64 columns
#pragma unroll 4
        for (int c = 0; c < 64; c++) {
            int cb = sh * 64 + c;
            float v = smem[sr * BM + (cb ^ (sr & 31))];
            int gcol = colB + cb;
            if (kbetter(v, gcol, tv[TK - 1], ti[TK - 1])) {
                tv[TK - 1] = v;
                ti[TK - 1] = gcol;
#pragma unroll
                for (int q = TK - 1; q > 0; --q) {
                    if (kbetter(tv[q], ti[q], tv[q - 1], ti[q - 1])) {
                        float t1 = tv[q]; tv[q] = tv[q - 1]; tv[q - 1] = t1;
                        int t2 = ti[q]; ti[q] = ti[q - 1]; ti[q - 1] = t2;
                    }
                }
            }
        }
    }
    __syncthreads();
    // merge the two halves of each row, write split-partial top-8
    float* mv = smem;                  // [128][2][8]
    int* mi = (int*)(smem + 2048);     // [128][2][8]
#pragma unroll
    for (int q = 0; q < TK; q++) {
        mv[(sr * 2 + sh) * TK + q] = tv[q];
        mi[(sr * 2 + sh) * TK + q] = ti[q];
    }
    __syncthreads();
    if (sh == 0) {
        int row = rowB + sr;
        unsigned used = 0;
        for (int o = 0; o < TK; o++) {
            float bv = -INFINITY;
            int bi = 0x7fffffff;
            int bsel = -1;
            for (int m = 0; m < 16; m++) {
                if ((used >> m) & 1u) continue;
                float v = mv[sr * 16 + m];
                int ix = mi[sr * 16 + m];
                if (bsel < 0 || kbetter(v, ix, bv, bi)) { bv = v; bi = ix; bsel = m; }
            }
            used |= 1u << bsel;
            pv[((size_t)row * CSPLIT + split) * TK + o] = bv;
            pi[((size_t)row * CSPLIT + split) * TK + o] = bi;
        }
    }
}

// ---------------------------------------------------------------- merge split partials -> final top-8
__global__ __launch_bounds__(256) void topk_merge_k(const float* __restrict__ pv,
                                                    const int* __restrict__ pi,
                                                    int* __restrict__ iknn,
                                                    float* __restrict__ dknn) {
    int row = blockIdx.x * 256 + threadIdx.x;
    if (row >= NN) return;
    unsigned long long used = 0;
    for (int o = 0; o < TK; o++) {
        float bv = -INFINITY;
        int bi = 0x7fffffff;
        int bsel = -1;
        for (int m = 0; m < CSPLIT * TK; m++) {
            if ((used >> m) & 1ull) continue;
            float v = pv[(size_t)row * CSPLIT * TK + m];
            int ix = pi[(size_t)row * CSPLIT * TK + m];
            if (bsel < 0 || kbetter(v, ix, bv, bi)) { bv = v; bi = ix; bsel = m; }
        }
        used |= 1ull << bsel;
        iknn[row * TK + o] = bi;
        dknn[row * TK + o] = bv;
    }
}

// ---------------------------------------------------------------- epilogue: masks + output
__global__ __launch_bounds__(256) void out_k(const int* __restrict__ iknn,
                                             const float* __restrict__ dknn,
                                             const unsigned int* __restrict__ bm,
                                             const int* __restrict__ labels,
                                             float* __restrict__ out) {
    int t = blockIdx.x * 256 + threadIdx.x;  // 0..65535
    int row = t >> 3;
    int ki = iknn[t];
    unsigned code = (unsigned)row * NN + (unsigned)ki;
    bool adj = (bm[code >> 5] >> (code & 31)) & 1u;
    bool close = false;
#pragma unroll
    for (int s = 0; s < KSEED; s++)
        close |= (labels[s * NN + row] == labels[s * NN + ki]);
    out[t] = (float)ki;
    out[NN * TK + t] = (adj || close) ? 1.0f : 0.0f;
    out[2 * NN * TK + t] = dknn[t];
}

// ----------------------------------------------------------------
extern "C" void kernel_launch(void* const* d_in, const int* in_sizes, int n_in,
                              void* d_out, int out_size, void* d_ws, size_t ws_size,
                              hipStream_t stream) {
    (void)n_in; (void)out_size; (void)ws_size;
    const float* student = (const float*)d_in[0];
    const float* teacher = (const float*)d_in[1];
    const int* edge = (const int*)d_in[2];
    const int* initIdx = (const int*)d_in[3];
    const int E = in_sizes[2] / 2;

    char* ws = (char*)d_ws;
    size_t off = 0;
    auto alloc = [&](size_t bytes) -> char* {
        char* p = ws + off;
        off += (bytes + 255) & ~(size_t)255;
        return p;
    };
    unsigned int* bm = (unsigned int*)alloc((size_t)NN * NN / 8);        // 8 MB
    float* sT = (float*)alloc((size_t)NN * DD * 4);                      // 8 MB
    float* tT = (float*)alloc((size_t)NN * DD * 4);                      // 8 MB
    float* centT = (float*)alloc((size_t)KSEED * DD * CC * 4);
    float* cnorm = (float*)alloc((size_t)KSEED * CC * 4);
    int* labels = (int*)alloc((size_t)KSEED * NN * 4);
    float* psums = (float*)alloc((size_t)KSEED * 32 * CC * DD * 4);      // 10.5 MB
    int* pcnts = (int*)alloc((size_t)KSEED * 32 * CC * 4);
    float* pv = (float*)alloc((size_t)NN * CSPLIT * TK * 4);
    int* pi = (int*)alloc((size_t)NN * CSPLIT * TK * 4);
    int* iknn = (int*)alloc((size_t)NN * TK * 4);
    float* dknn = (float*)alloc((size_t)NN * TK * 4);
    float* out = (float*)d_out;

    hipMemsetAsync(bm, 0, (size_t)NN * NN / 8, stream);
    adj_k<<<dim3((E + 255) / 256), 256, 0, stream>>>(edge, edge + E, bm, E);
    transpose_k<<<dim3(NN / 32, DD / 32), dim3(32, 8), 0, stream>>>(student, sT);
    transpose_k<<<dim3(NN / 32, DD / 32), dim3(32, 8), 0, stream>>>(teacher, tT);

    kinit_k<<<dim3(CC, KSEED), 256, 0, stream>>>(teacher, initIdx, centT, cnorm);
    for (int it = 0; it < NITERS; ++it) {
        kassign_k<<<dim3(NN / 128, KSEED), 256, 0, stream>>>(tT, centT, cnorm, labels);
        kupd1_k<<<dim3(32, KSEED), 256, 0, stream>>>(teacher, labels, psums, pcnts);
        kupd2_k<<<dim3(CC, KSEED), 256, 0, stream>>>(psums, pcnts, centT, cnorm);
    }
    kassign_k<<<dim3(NN / 128, KSEED), 256, 0, stream>>>(tT, centT, cnorm, labels);

    topk_gemm_k<<<dim3(CSPLIT, NN / BM), 256, 0, stream>>>(sT, tT, pv, pi);
    topk_merge_k<<<dim3((NN + 255) / 256), 256, 0, stream>>>(pv, pi, iknn, dknn);
    out_k<<<dim3(NN * TK / 256), 256, 0, stream>>>(iknn, dknn, bm, labels, out);
}

// Round 2
// 3955.163 us; speedup vs baseline: 2.6457x; 2.6457x over previous
//
#include <hip/hip_runtime.h>
#include <hip/hip_bf16.h>
#include <math.h>

#define NN 8192
#define DD 256
#define KSEED 5
#define CC 64
#define TK 8
#define NITERS 20
#define CSPLIT 8
#define BM 128
#define BN 128
#define BK 64

__device__ __forceinline__ bool kbetter(float v1, int i1, float v2, int i2) {
    return (v1 > v2) || ((v1 == v2) && (i1 < i2));
}

// ---------------------------------------------------------------- transpose
// in [NN][DD] -> out [DD][NN]
__global__ __launch_bounds__(256) void transpose_k(const float* __restrict__ in,
                                                   float* __restrict__ out) {
    __shared__ float t[32][33];
    int bx = blockIdx.x * 32;  // N base
    int by = blockIdx.y * 32;  // D base
    int x = threadIdx.x;       // 0..31
    int y = threadIdx.y;       // 0..7
#pragma unroll
    for (int i = 0; i < 32; i += 8)
        t[y + i][x] = in[(size_t)(bx + y + i) * DD + by + x];
    __syncthreads();
#pragma unroll
    for (int i = 0; i < 32; i += 8)
        out[(size_t)(by + y + i) * NN + bx + x] = t[x][y + i];
}

// ---------------------------------------------------------------- adjacency bitmap
__global__ __launch_bounds__(256) void adj_k(const int* __restrict__ e0,
                                             const int* __restrict__ e1,
                                             unsigned int* __restrict__ bm, int E) {
    int t = blockIdx.x * 256 + threadIdx.x;
    if (t < E) {
        unsigned code = (unsigned)e0[t] * NN + (unsigned)e1[t];
        atomicOr(&bm[code >> 5], 1u << (code & 31));
    }
}

// ---------------------------------------------------------------- kmeans init
// centT layout: [s][d][c]
__global__ __launch_bounds__(256) void kinit_k(const float* __restrict__ teacher,
                                               const int* __restrict__ initIdx,
                                               float* __restrict__ centT,
                                               float* __restrict__ cnorm) {
    int c = blockIdx.x, s = blockIdx.y;
    int t = threadIdx.x;
    int src = initIdx[s * CC + c];
    float v = teacher[(size_t)src * DD + t];
    centT[((size_t)s * DD + t) * CC + c] = v;
    __shared__ float red[256];
    red[t] = v * v;
    __syncthreads();
    for (int w = 128; w > 0; w >>= 1) {
        if (t < w) red[t] += red[t + w];
        __syncthreads();
    }
    if (t == 0) cnorm[s * CC + c] = red[0];
}

// ---------------------------------------------------------------- kmeans assign
// 64 points x 64 clusters per block; 4x4 thread tile (16 acc regs).
// d2 = ||c||^2 - 2 x.c ; argmin over c (ties -> lowest c)
__global__ __launch_bounds__(256) void kassign_k(const float* __restrict__ tT,
                                                 const float* __restrict__ centT,
                                                 const float* __restrict__ cnorm,
                                                 int* __restrict__ labels) {
    __shared__ float Xs[64 * 64];  // [kk][pt] 16 KB
    __shared__ float Cs[64 * 64];  // [kk][c]  16 KB (reused for argmin reduce)
    const int s = blockIdx.y;
    const int pB = blockIdx.x * 64;
    const int tid = threadIdx.x;
    const int tx = tid & 15;   // cluster group: 4tx..4tx+3
    const int ty = tid >> 4;   // point group: 4ty..4ty+3
    float acc[4][4];
#pragma unroll
    for (int a = 0; a < 4; a++)
#pragma unroll
        for (int b = 0; b < 4; b++) acc[a][b] = 0.f;

    for (int kt = 0; kt < DD; kt += 64) {
        __syncthreads();
#pragma unroll
        for (int m = 0; m < 4; m++) {
            int u = m * 256 + tid;
            int kk = u >> 4;
            int p4 = (u & 15) << 2;
            *(float4*)&Xs[kk * 64 + p4] =
                *(const float4*)&tT[(size_t)(kt + kk) * NN + pB + p4];
            *(float4*)&Cs[kk * 64 + p4] =
                *(const float4*)&centT[((size_t)s * DD + kt + kk) * CC + p4];
        }
        __syncthreads();
#pragma unroll 8
        for (int kk = 0; kk < 64; kk++) {
            float4 x4 = *(float4*)&Xs[kk * 64 + 4 * ty];
            float4 c4 = *(float4*)&Cs[kk * 64 + 4 * tx];
            float xr[4] = {x4.x, x4.y, x4.z, x4.w};
            float cr[4] = {c4.x, c4.y, c4.z, c4.w};
#pragma unroll
            for (int a = 0; a < 4; a++)
#pragma unroll
                for (int b = 0; b < 4; b++) acc[a][b] = fmaf(xr[a], cr[b], acc[a][b]);
        }
    }
    __syncthreads();
    float* red = Cs;  // [64 pts][16 tx][2] = 2048 floats
    float cn[4];
#pragma unroll
    for (int b = 0; b < 4; b++) cn[b] = cnorm[s * CC + 4 * tx + b];
#pragma unroll
    for (int a = 0; a < 4; a++) {
        float bv = INFINITY;
        int bc = 0;
#pragma unroll
        for (int b = 0; b < 4; b++) {
            float d = fmaf(-2.f, acc[a][b], cn[b]);
            if (d < bv) { bv = d; bc = 4 * tx + b; }
        }
        int p = 4 * ty + a;
        red[(p * 16 + tx) * 2] = bv;
        ((int*)red)[(p * 16 + tx) * 2 + 1] = bc;
    }
    __syncthreads();
    if (tid < 64) {
        float bv = INFINITY;
        int bc = 0;
        for (int t2 = 0; t2 < 16; t2++) {  // ascending c -> lowest-c tie-break
            float v = red[(tid * 16 + t2) * 2];
            int c = ((int*)red)[(tid * 16 + t2) * 2 + 1];
            if (v < bv) { bv = v; bc = c; }
        }
        labels[(size_t)s * NN + pB + tid] = bc;
    }
}

// ---------------------------------------------------------------- kmeans update: partial sums
__global__ __launch_bounds__(256) void kupd1_k(const float* __restrict__ teacher,
                                               const int* __restrict__ labels,
                                               float* __restrict__ psums,
                                               int* __restrict__ pcnts) {
    __shared__ float sums[CC * DD];  // 64 KB
    __shared__ int labs[256];
    const int b = blockIdx.x;
    const int s = blockIdx.y;
    const int tid = threadIdx.x;
    for (int i = tid; i < CC * DD; i += 256) sums[i] = 0.f;
    const int p0 = b * 256;
    labs[tid] = labels[(size_t)s * NN + p0 + tid];
    __syncthreads();
#pragma unroll 4
    for (int i = 0; i < 256; i++) {
        int lab = labs[i];
        float x = teacher[(size_t)(p0 + i) * DD + tid];
        atomicAdd(&sums[lab * DD + tid], x);  // ds_add_f32, fire-and-forget
    }
    __syncthreads();
    for (int i = tid; i < CC * DD; i += 256)
        psums[(size_t)(s * 32 + b) * CC * DD + i] = sums[i];
    if (tid < CC) {
        int cnt = 0;
        for (int i = 0; i < 256; i++) cnt += (labs[i] == tid);
        pcnts[(s * 32 + b) * CC + tid] = cnt;
    }
}

// ---------------------------------------------------------------- kmeans update: reduce + new centroids + cnorm
__global__ __launch_bounds__(256) void kupd2_k(const float* __restrict__ psums,
                                               const int* __restrict__ pcnts,
                                               float* __restrict__ centT,
                                               float* __restrict__ cnorm) {
    const int c = blockIdx.x;
    const int s = blockIdx.y;
    const int t = threadIdx.x;
    float sum = 0.f;
#pragma unroll 4
    for (int b = 0; b < 32; b++) sum += psums[((size_t)(s * 32 + b) * CC + c) * DD + t];
    int cnt = 0;
#pragma unroll
    for (int b = 0; b < 32; b++) cnt += pcnts[(s * 32 + b) * CC + c];
    float old = centT[((size_t)s * DD + t) * CC + c];
    float nv = (cnt > 0) ? (sum / (float)cnt) : old;
    centT[((size_t)s * DD + t) * CC + c] = nv;
    __shared__ float red[256];
    red[t] = nv * nv;
    __syncthreads();
    for (int w = 128; w > 0; w >>= 1) {
        if (t < w) red[t] += red[t + w];
        __syncthreads();
    }
    if (t == 0) cnorm[s * CC + c] = red[0];
}

// ---------------------------------------------------------------- fused GEMM + per-row top-8 (per column split)
__global__ __launch_bounds__(256) void topk_gemm_k(const float* __restrict__ sT,
                                                   const float* __restrict__ tT,
                                                   float* __restrict__ pv,
                                                   int* __restrict__ pi) {
    __shared__ float smem[BK * BM + BK * BN];  // 64 KB, multi-purpose
    float* As = smem;            // [BK][BM] k-major
    float* Bs = smem + BK * BM;  // [BK][BN]

    const int split = blockIdx.x;
    const int rowB = blockIdx.y * BM;
    const int tid = threadIdx.x;
    const int tx = tid & 15;
    const int ty = tid >> 4;
    const int sr = tid >> 1;  // scan row 0..127
    const int sh = tid & 1;   // scan half

    float tv[TK];
    int ti[TK];
#pragma unroll
    for (int q = 0; q < TK; q++) { tv[q] = -INFINITY; ti[q] = 0x7fffffff; }

    const int colBase = split * (NN / CSPLIT);

    for (int ct = 0; ct < NN / CSPLIT; ct += BN) {
        const int colB = colBase + ct;
        float acc[8][8];
#pragma unroll
        for (int a = 0; a < 8; a++)
#pragma unroll
            for (int b = 0; b < 8; b++) acc[a][b] = 0.f;

        for (int kt = 0; kt < DD; kt += BK) {
            __syncthreads();
#pragma unroll
            for (int m = 0; m < 8; m++) {
                int u = m * 256 + tid;
                int kk = u >> 5;
                int r4 = (u & 31) << 2;
                *(float4*)&As[kk * BM + r4] =
                    *(const float4*)&sT[(size_t)(kt + kk) * NN + rowB + r4];
                *(float4*)&Bs[kk * BN + r4] =
                    *(const float4*)&tT[(size_t)(kt + kk) * NN + colB + r4];
            }
            __syncthreads();
#pragma unroll
            for (int kk = 0; kk < BK; kk++) {
                float4 a0 = *(float4*)&As[kk * BM + 4 * ty];
                float4 a1 = *(float4*)&As[kk * BM + 64 + 4 * ty];
                float4 b0 = *(float4*)&Bs[kk * BN + 4 * tx];
                float4 b1 = *(float4*)&Bs[kk * BN + 64 + 4 * tx];
                float ar[8] = {a0.x, a0.y, a0.z, a0.w, a1.x, a1.y, a1.z, a1.w};
                float bc[8] = {b0.x, b0.y, b0.z, b0.w, b1.x, b1.y, b1.z, b1.w};
#pragma unroll
                for (int a = 0; a < 8; a++)
#pragma unroll
                    for (int b = 0; b < 8; b++)
                        acc[a][b] = fmaf(ar[a], bc[b], acc[a][b]);
            }
        }
        __syncthreads();
        // stage tile to LDS with XOR bank swizzle (+ diagonal boost)
#pragma unroll
        for (int a = 0; a < 8; a++) {
            int ra = (a < 4) ? (4 * ty + a) : (64 + 4 * ty + (a - 4));
            int grow = rowB + ra;
#pragma unroll
            for (int b = 0; b < 8; b++) {
                int cb = (b < 4) ? (4 * tx + b) : (64 + 4 * tx + (b - 4));
                float v = acc[a][b];
                if (grow == colB + cb) v += 10.f;
                smem[ra * BM + (cb ^ (ra & 31))] = v;
            }
        }
        __syncthreads();
        // per-thread running top-8 over this tile's 64 columns
#pragma unroll 4
        for (int c = 0; c < 64; c++) {
            int cb = sh * 64 + c;
            float v = smem[sr * BM + (cb ^ (sr & 31))];
            int gcol = colB + cb;
            if (kbetter(v, gcol, tv[TK - 1], ti[TK - 1])) {
                tv[TK - 1] = v;
                ti[TK - 1] = gcol;
#pragma unroll
                for (int q = TK - 1; q > 0; --q) {
                    if (kbetter(tv[q], ti[q], tv[q - 1], ti[q - 1])) {
                        float t1 = tv[q]; tv[q] = tv[q - 1]; tv[q - 1] = t1;
                        int t2 = ti[q]; ti[q] = ti[q - 1]; ti[q - 1] = t2;
                    }
                }
            }
        }
    }
    __syncthreads();
    // merge the two halves of each row, write split-partial top-8
    float* mv = smem;                  // [128][2][8]
    int* mi = (int*)(smem + 2048);     // [128][2][8]
#pragma unroll
    for (int q = 0; q < TK; q++) {
        mv[(sr * 2 + sh) * TK + q] = tv[q];
        mi[(sr * 2 + sh) * TK + q] = ti[q];
    }
    __syncthreads();
    if (sh == 0) {
        int row = rowB + sr;
        unsigned used = 0;
        for (int o = 0; o < TK; o++) {
            float bv = -INFINITY;
            int bi = 0x7fffffff;
            int bsel = -1;
            for (int m = 0; m < 16; m++) {
                if ((used >> m) & 1u) continue;
                float v = mv[sr * 16 + m];
                int ix = mi[sr * 16 + m];
                if (bsel < 0 || kbetter(v, ix, bv, bi)) { bv = v; bi = ix; bsel = m; }
            }
            used |= 1u << bsel;
            pv[((size_t)row * CSPLIT + split) * TK + o] = bv;
            pi[((size_t)row * CSPLIT + split) * TK + o] = bi;
        }
    }
}

// ---------------------------------------------------------------- merge split partials -> final top-8
__global__ __launch_bounds__(256) void topk_merge_k(const float* __restrict__ pv,
                                                    const int* __restrict__ pi,
                                                    int* __restrict__ iknn,
                                                    float* __restrict__ dknn) {
    int row = blockIdx.x * 256 + threadIdx.x;
    if (row >= NN) return;
    unsigned long long used = 0;
    for (int o = 0; o < TK; o++) {
        float bv = -INFINITY;
        int bi = 0x7fffffff;
        int bsel = -1;
        for (int m = 0; m < CSPLIT * TK; m++) {
            if ((used >> m) & 1ull) continue;
            float v = pv[(size_t)row * CSPLIT * TK + m];
            int ix = pi[(size_t)row * CSPLIT * TK + m];
            if (bsel < 0 || kbetter(v, ix, bv, bi)) { bv = v; bi = ix; bsel = m; }
        }
        used |= 1ull << bsel;
        iknn[row * TK + o] = bi;
        dknn[row * TK + o] = bv;
    }
}

// ---------------------------------------------------------------- epilogue: masks + output
__global__ __launch_bounds__(256) void out_k(const int* __restrict__ iknn,
                                             const float* __restrict__ dknn,
                                             const unsigned int* __restrict__ bm,
                                             const int* __restrict__ labels,
                                             float* __restrict__ out) {
    int t = blockIdx.x * 256 + threadIdx.x;  // 0..65535
    int row = t >> 3;
    int ki = iknn[t];
    unsigned code = (unsigned)row * NN + (unsigned)ki;
    bool adj = (bm[code >> 5] >> (code & 31)) & 1u;
    bool close = false;
#pragma unroll
    for (int s = 0; s < KSEED; s++)
        close |= (labels[s * NN + row] == labels[s * NN + ki]);
    out[t] = (float)ki;
    out[NN * TK + t] = (adj || close) ? 1.0f : 0.0f;
    out[2 * NN * TK + t] = dknn[t];
}

// ----------------------------------------------------------------
extern "C" void kernel_launch(void* const* d_in, const int* in_sizes, int n_in,
                              void* d_out, int out_size, void* d_ws, size_t ws_size,
                              hipStream_t stream) {
    (void)n_in; (void)out_size; (void)ws_size;
    const float* student = (const float*)d_in[0];
    const float* teacher = (const float*)d_in[1];
    const int* edge = (const int*)d_in[2];
    const int* initIdx = (const int*)d_in[3];
    const int E = in_sizes[2] / 2;

    char* ws = (char*)d_ws;
    size_t off = 0;
    auto alloc = [&](size_t bytes) -> char* {
        char* p = ws + off;
        off += (bytes + 255) & ~(size_t)255;
        return p;
    };
    unsigned int* bm = (unsigned int*)alloc((size_t)NN * NN / 8);        // 8 MB
    float* sT = (float*)alloc((size_t)NN * DD * 4);                      // 8 MB
    float* tT = (float*)alloc((size_t)NN * DD * 4);                      // 8 MB
    float* centT = (float*)alloc((size_t)KSEED * DD * CC * 4);
    float* cnorm = (float*)alloc((size_t)KSEED * CC * 4);
    int* labels = (int*)alloc((size_t)KSEED * NN * 4);
    float* psums = (float*)alloc((size_t)KSEED * 32 * CC * DD * 4);      // 10.5 MB
    int* pcnts = (int*)alloc((size_t)KSEED * 32 * CC * 4);
    float* pv = (float*)alloc((size_t)NN * CSPLIT * TK * 4);
    int* pi = (int*)alloc((size_t)NN * CSPLIT * TK * 4);
    int* iknn = (int*)alloc((size_t)NN * TK * 4);
    float* dknn = (float*)alloc((size_t)NN * TK * 4);
    float* out = (float*)d_out;

    hipMemsetAsync(bm, 0, (size_t)NN * NN / 8, stream);
    adj_k<<<dim3((E + 255) / 256), 256, 0, stream>>>(edge, edge + E, bm, E);
    transpose_k<<<dim3(NN / 32, DD / 32), dim3(32, 8), 0, stream>>>(student, sT);
    transpose_k<<<dim3(NN / 32, DD / 32), dim3(32, 8), 0, stream>>>(teacher, tT);

    kinit_k<<<dim3(CC, KSEED), 256, 0, stream>>>(teacher, initIdx, centT, cnorm);
    for (int it = 0; it < NITERS; ++it) {
        kassign_k<<<dim3(NN / 64, KSEED), 256, 0, stream>>>(tT, centT, cnorm, labels);
        kupd1_k<<<dim3(32, KSEED), 256, 0, stream>>>(teacher, labels, psums, pcnts);
        kupd2_k<<<dim3(CC, KSEED), 256, 0, stream>>>(psums, pcnts, centT, cnorm);
    }
    kassign_k<<<dim3(NN / 64, KSEED), 256, 0, stream>>>(tT, centT, cnorm, labels);

    topk_gemm_k<<<dim3(CSPLIT, NN / BM), 256, 0, stream>>>(sT, tT, pv, pi);
    topk_merge_k<<<dim3((NN + 255) / 256), 256, 0, stream>>>(pv, pi, iknn, dknn);
    out_k<<<dim3(NN * TK / 256), 256, 0, stream>>>(iknn, dknn, bm, labels, out);
}